// Round 7
// baseline (264.143 us; speedup 1.0000x reference)
//
#include <hip/hip_runtime.h>
#include <math.h>

#define LVL 16
#define TBL 65536
#define BATCH 8
#define NPIX 65536       // 256*256
#define SDIM 512
#define HPRIME 2654435761u

typedef __attribute__((ext_vector_type(2))) float f32x2;

struct ResPack { int r[LVL]; };

// ws layout (floats): [0, 17152) weff (8 batches x 2144, paired layout)
#define WEFF_STRIDE 2144

// ---------------------------------------------------------------------------
// Kernel A: fused style + demod + weff emit (ran clean in rounds 1/5).
// Grid 24 blocks: b = blk&7, l = blk>>3 (layer). Each block computes its
// layer's 32 style dots, demod, and emits its weff slice (paired layout).
// ---------------------------------------------------------------------------
__global__ __launch_bounds__(256) void weff_kernel(
    const float* __restrict__ s,
    const float* __restrict__ aw0, const float* __restrict__ ab0,
    const float* __restrict__ aw1, const float* __restrict__ ab1,
    const float* __restrict__ aw2, const float* __restrict__ ab2,
    const float* __restrict__ w0, const float* __restrict__ w1,
    const float* __restrict__ w2,
    float* __restrict__ ws)
{
    const int b = blockIdx.x & 7;
    const int l = blockIdx.x >> 3;
    const int tid = (int)threadIdx.x;
    const int wave = tid >> 6, lane = tid & 63;

    const float* aw; const float* ab; const float* w; int nout;
    if (l == 0)      { aw = aw0; ab = ab0; w = w0; nout = 32; }
    else if (l == 1) { aw = aw1; ab = ab1; w = w1; nout = 32; }
    else             { aw = aw2; ab = ab2; w = w2; nout = 3;  }

    __shared__ float st[32];
    __shared__ float dem[32];

    // ---- style: 32 rows x dot(512). 4 waves x 8 rows, 2 chains per iter.
    const float* sb = s + b * SDIM;
    for (int r0 = wave * 8; r0 < wave * 8 + 8; r0 += 2) {
        const float* rowA = aw + (size_t)r0 * SDIM;
        const float* rowB = aw + (size_t)(r0 + 1) * SDIM;
        float a0 = 0.f, a1 = 0.f;
        #pragma unroll
        for (int j = 0; j < SDIM / 64; ++j) {
            const int k = lane + j * 64;
            const float sv = sb[k];
            a0 += sv * rowA[k];
            a1 += sv * rowB[k];
        }
        #pragma unroll
        for (int off = 32; off >= 1; off >>= 1) {
            a0 += __shfl_xor(a0, off, 64);
            a1 += __shfl_xor(a1, off, 64);
        }
        if (lane == 0) { st[r0] = a0 + ab[r0]; st[r0 + 1] = a1 + ab[r0 + 1]; }
    }
    __syncthreads();

    // ---- demod: o = tid>>3 (0..31), 8 lanes each sum 4 squares + butterfly.
    {
        const int o = tid >> 3, sub = tid & 7;
        if (o < nout) {
            float sum = 0.f;
            #pragma unroll
            for (int j = 0; j < 4; ++j) {
                const int i = sub * 4 + j;
                const float v = w[o * 32 + i] * st[i];
                sum += v * v;
            }
            sum += __shfl_xor(sum, 4, 64);
            sum += __shfl_xor(sum, 2, 64);
            sum += __shfl_xor(sum, 1, 64);
            if (sub == 0) dem[o] = 1.0f / sqrtf(sum + 1e-8f);
        }
    }
    __syncthreads();

    // ---- emit paired layout (same formulas/order as the verified kernel).
    float* outp = ws + (size_t)b * WEFF_STRIDE;
    if (l < 2) {
        const int base = l * 1024;
        for (int idx = tid; idx < 1024; idx += 256) {
            const int o2 = idx >> 6, rem = idx & 63, i = rem >> 1, h = rem & 1;
            const int oo = o2 + 16 * h;
            outp[base + idx] = w[oo * 32 + i] * st[i] * dem[oo];
        }
    } else {
        if (tid < 96) {
            const int oo = tid >> 5, i = tid & 31;
            outp[2048 + tid] = w[tid] * st[i] * dem[oo];
        }
    }
}

// ---------------------------------------------------------------------------
// Kernel B: independent-thread hash-grid + MLP, TWO pixels per thread.
// No LDS, no barriers (round-0 structure — the measured best). Each thread
// handles column tid of rows 2*chunk and 2*chunk+1: every weight load feeds
// two FMA pairs (per-pixel weight-load instr halved) and the two independent
// accumulator chains double FMA ILP. Layer 0 is streamed per level (i-outer)
// so feat[] never lives in 64 registers and level l+1's gathers overlap
// level l's 64 pk-FMAs. Per-accumulator summation order is IDENTICAL to the
// verified kernel (bias, then i = 0..31 ascending).
// ---------------------------------------------------------------------------
__global__ __launch_bounds__(256) void fused_kernel(
    const float* __restrict__ tables,   // [B, L, T, 2]
    const float* __restrict__ coords,   // [N, 2]
    const float* __restrict__ weff,     // ws: paired weights per batch
    const float* __restrict__ b0, const float* __restrict__ b1, const float* __restrict__ b2,
    float* __restrict__ out,            // [B, 3, 256, 256]
    ResPack res)
{
    const int b     = blockIdx.x & 7;           // XCD-affinity: batch <-> XCD
    const int chunk = blockIdx.x >> 3;          // 128 chunks = 2 rows each
    const int tid   = (int)threadIdx.x;
    const int nA    = chunk * 512 + tid;
    const int nB    = nA + 256;

    const float cxA = coords[2 * nA], cyA = coords[2 * nA + 1];
    const float cxB = coords[2 * nB], cyB = coords[2 * nB + 1];
    const float* tb = tables + (size_t)b * (LVL * TBL * 2);

    const f32x2* W0p = (const f32x2*)(weff + (size_t)b * WEFF_STRIDE);         // [16][32]
    const f32x2* W1p = W0p + 512;                                              // [16][32]
    const float* W2  = weff + (size_t)b * WEFF_STRIDE + 2048;                  // [3][32]

    // ---- layer-0 accumulators (paired outputs {o2, o2+16}), both pixels ----
    f32x2 aA[16], aB[16];
    #pragma unroll
    for (int o2 = 0; o2 < 16; ++o2) {
        f32x2 init; init[0] = b0[o2]; init[1] = b0[o2 + 16];
        aA[o2] = init; aB[o2] = init;
    }

    // ---- streamed gather + layer-0 fold, one level at a time ----
    #pragma unroll
    for (int l = 0; l < LVL; ++l) {
        const int R = res.r[l];
        const float rm1 = (float)(R - 1);
        const unsigned im = (unsigned)(R - 1);
        const float2* tl = (const float2*)(tb + l * (TBL * 2));

        // pixel A addresses
        const float pxA = cxA * rm1, pyA = cyA * rm1;
        const float fpxA = floorf(pxA), fpyA = floorf(pyA);
        const float fxA = pxA - fpxA, fyA = pyA - fpyA;
        unsigned xA0 = (unsigned)fpxA, yA0 = (unsigned)fpyA;
        unsigned xA1 = xA0 + 1u; if (xA1 > im) xA1 = im;
        unsigned yA1 = yA0 + 1u; if (yA1 > im) yA1 = im;
        const unsigned hyA0 = yA0 * HPRIME, hyA1 = yA1 * HPRIME;
        // pixel B addresses
        const float pxB = cxB * rm1, pyB = cyB * rm1;
        const float fpxB = floorf(pxB), fpyB = floorf(pyB);
        const float fxB = pxB - fpxB, fyB = pyB - fpyB;
        unsigned xB0 = (unsigned)fpxB, yB0 = (unsigned)fpyB;
        unsigned xB1 = xB0 + 1u; if (xB1 > im) xB1 = im;
        unsigned yB1 = yB0 + 1u; if (yB1 > im) yB1 = im;
        const unsigned hyB0 = yB0 * HPRIME, hyB1 = yB1 * HPRIME;

        // 8 gathers issued together
        const float2 gA00 = tl[(xA0 ^ hyA0) & 0xFFFFu];
        const float2 gA10 = tl[(xA1 ^ hyA0) & 0xFFFFu];
        const float2 gA01 = tl[(xA0 ^ hyA1) & 0xFFFFu];
        const float2 gA11 = tl[(xA1 ^ hyA1) & 0xFFFFu];
        const float2 gB00 = tl[(xB0 ^ hyB0) & 0xFFFFu];
        const float2 gB10 = tl[(xB1 ^ hyB0) & 0xFFFFu];
        const float2 gB01 = tl[(xB0 ^ hyB1) & 0xFFFFu];
        const float2 gB11 = tl[(xB1 ^ hyB1) & 0xFFFFu];

        const float wA00 = (1.f - fxA) * (1.f - fyA);
        const float wA10 = fxA * (1.f - fyA);
        const float wA01 = (1.f - fxA) * fyA;
        const float wA11 = fxA * fyA;
        const float fA0 = gA00.x * wA00 + gA10.x * wA10 + gA01.x * wA01 + gA11.x * wA11;
        const float fA1 = gA00.y * wA00 + gA10.y * wA10 + gA01.y * wA01 + gA11.y * wA11;

        const float wB00 = (1.f - fxB) * (1.f - fyB);
        const float wB10 = fxB * (1.f - fyB);
        const float wB01 = (1.f - fxB) * fyB;
        const float wB11 = fxB * fyB;
        const float fB0 = gB00.x * wB00 + gB10.x * wB10 + gB01.x * wB01 + gB11.x * wB11;
        const float fB1 = gB00.y * wB00 + gB10.y * wB10 + gB01.y * wB01 + gB11.y * wB11;

        // fold features i = 2l, 2l+1 into all paired accumulators;
        // each weight load serves both pixels.
        #pragma unroll
        for (int o2 = 0; o2 < 16; ++o2) {
            const f32x2 w0v = W0p[o2 * 32 + 2 * l];
            const f32x2 w1v = W0p[o2 * 32 + 2 * l + 1];
            f32x2 t;
            t[0] = fA0; t[1] = fA0; aA[o2] += w0v * t;
            t[0] = fA1; t[1] = fA1; aA[o2] += w1v * t;
            t[0] = fB0; t[1] = fB0; aB[o2] += w0v * t;
            t[0] = fB1; t[1] = fB1; aB[o2] += w1v * t;
        }
    }

    // relu -> h1 (aA/aB become layer-0 activations)
    #pragma unroll
    for (int o2 = 0; o2 < 16; ++o2) {
        aA[o2][0] = fmaxf(aA[o2][0], 0.f); aA[o2][1] = fmaxf(aA[o2][1], 0.f);
        aB[o2][0] = fmaxf(aB[o2][0], 0.f); aB[o2][1] = fmaxf(aB[o2][1], 0.f);
    }

    // ---- layer 1 (shared weight loads, two chains) ----
    f32x2 h2A[16], h2B[16];
    #pragma unroll
    for (int o2 = 0; o2 < 16; ++o2) {
        f32x2 accA; accA[0] = b1[o2]; accA[1] = b1[o2 + 16];
        f32x2 accB = accA;
        #pragma unroll
        for (int i = 0; i < 32; ++i) {
            const f32x2 w = W1p[o2 * 32 + i];
            const float hvA = aA[i & 15][i >> 4];
            const float hvB = aB[i & 15][i >> 4];
            f32x2 t;
            t[0] = hvA; t[1] = hvA; accA += w * t;
            t[0] = hvB; t[1] = hvB; accB += w * t;
        }
        accA[0] = fmaxf(accA[0], 0.f); accA[1] = fmaxf(accA[1], 0.f);
        accB[0] = fmaxf(accB[0], 0.f); accB[1] = fmaxf(accB[1], 0.f);
        h2A[o2] = accA; h2B[o2] = accB;
    }

    // ---- layer 2 (3 outputs, shared weight loads) ----
    #pragma unroll
    for (int o = 0; o < 3; ++o) {
        float accA = b2[o], accB = b2[o];
        #pragma unroll
        for (int i = 0; i < 32; ++i) {
            const float w = W2[o * 32 + i];
            accA = fmaf(w, h2A[i & 15][i >> 4], accA);
            accB = fmaf(w, h2B[i & 15][i >> 4], accB);
        }
        const size_t base = (size_t)(b * 3 + o) << 16;
        out[base + nA] = tanhf(accA);
        out[base + nB] = tanhf(accB);
    }
}

// ---------------------------------------------------------------------------
extern "C" void kernel_launch(void* const* d_in, const int* in_sizes, int n_in,
                              void* d_out, int out_size, void* d_ws, size_t ws_size,
                              hipStream_t stream) {
    const float* x      = (const float*)d_in[0];
    const float* s      = (const float*)d_in[1];
    const float* coords = (const float*)d_in[2];
    const float* w0  = (const float*)d_in[3];
    const float* aw0 = (const float*)d_in[4];
    const float* ab0 = (const float*)d_in[5];
    const float* b0  = (const float*)d_in[6];
    const float* w1  = (const float*)d_in[7];
    const float* aw1 = (const float*)d_in[8];
    const float* ab1 = (const float*)d_in[9];
    const float* b1  = (const float*)d_in[10];
    const float* w2  = (const float*)d_in[11];
    const float* aw2 = (const float*)d_in[12];
    const float* ab2 = (const float*)d_in[13];
    const float* b2  = (const float*)d_in[14];
    float* out = (float*)d_out;
    float* ws  = (float*)d_ws;    // 17152 floats used

    ResPack rp;
    const double g = pow(256.0 / 16.0, 1.0 / 15.0);
    for (int l = 0; l < LVL; ++l) {
        double r = 16.0 * pow(g, (double)l);
        long ri = lround(r);
        if (ri > 256) ri = 256;
        rp.r[l] = (int)ri;
    }

    hipLaunchKernelGGL(weff_kernel, dim3(24), dim3(256), 0, stream,
                       s, aw0, ab0, aw1, ab1, aw2, ab2, w0, w1, w2, ws);
    hipLaunchKernelGGL(fused_kernel, dim3(128 * BATCH), dim3(256), 0, stream,
                       x, coords, ws, b0, b1, b2, out, rp);
}

// Round 9
// 164.610 us; speedup vs baseline: 1.6047x; 1.6047x over previous
//
#include <hip/hip_runtime.h>
#include <math.h>

#define LVL 16
#define TBL 65536
#define BATCH 8
#define NPIX 65536       // 256*256
#define SDIM 512
#define HPRIME 2654435761u

typedef __attribute__((ext_vector_type(2))) float f32x2;

struct ResPack { int r[LVL]; };

// ws layout (floats): [0, 17152) weff (8 batches x 2144, paired layout)
#define WEFF_STRIDE 2144

// ---------------------------------------------------------------------------
// Kernel A: fused style + demod + weff emit (ran clean in rounds 5/7).
// Grid 24 blocks: b = blk&7, l = blk>>3 (layer). Each block computes its
// layer's 32 style dots, demod, and emits its weff slice (paired layout).
// ---------------------------------------------------------------------------
__global__ __launch_bounds__(256) void weff_kernel(
    const float* __restrict__ s,
    const float* __restrict__ aw0, const float* __restrict__ ab0,
    const float* __restrict__ aw1, const float* __restrict__ ab1,
    const float* __restrict__ aw2, const float* __restrict__ ab2,
    const float* __restrict__ w0, const float* __restrict__ w1,
    const float* __restrict__ w2,
    float* __restrict__ ws)
{
    const int b = blockIdx.x & 7;
    const int l = blockIdx.x >> 3;
    const int tid = (int)threadIdx.x;
    const int wave = tid >> 6, lane = tid & 63;

    const float* aw; const float* ab; const float* w; int nout;
    if (l == 0)      { aw = aw0; ab = ab0; w = w0; nout = 32; }
    else if (l == 1) { aw = aw1; ab = ab1; w = w1; nout = 32; }
    else             { aw = aw2; ab = ab2; w = w2; nout = 3;  }

    __shared__ float st[32];
    __shared__ float dem[32];

    // ---- style: 32 rows x dot(512). 4 waves x 8 rows, 2 chains per iter.
    const float* sb = s + b * SDIM;
    for (int r0 = wave * 8; r0 < wave * 8 + 8; r0 += 2) {
        const float* rowA = aw + (size_t)r0 * SDIM;
        const float* rowB = aw + (size_t)(r0 + 1) * SDIM;
        float a0 = 0.f, a1 = 0.f;
        #pragma unroll
        for (int j = 0; j < SDIM / 64; ++j) {
            const int k = lane + j * 64;
            const float sv = sb[k];
            a0 += sv * rowA[k];
            a1 += sv * rowB[k];
        }
        #pragma unroll
        for (int off = 32; off >= 1; off >>= 1) {
            a0 += __shfl_xor(a0, off, 64);
            a1 += __shfl_xor(a1, off, 64);
        }
        if (lane == 0) { st[r0] = a0 + ab[r0]; st[r0 + 1] = a1 + ab[r0 + 1]; }
    }
    __syncthreads();

    // ---- demod: o = tid>>3 (0..31), 8 lanes each sum 4 squares + butterfly.
    {
        const int o = tid >> 3, sub = tid & 7;
        if (o < nout) {
            float sum = 0.f;
            #pragma unroll
            for (int j = 0; j < 4; ++j) {
                const int i = sub * 4 + j;
                const float v = w[o * 32 + i] * st[i];
                sum += v * v;
            }
            sum += __shfl_xor(sum, 4, 64);
            sum += __shfl_xor(sum, 2, 64);
            sum += __shfl_xor(sum, 1, 64);
            if (sub == 0) dem[o] = 1.0f / sqrtf(sum + 1e-8f);
        }
    }
    __syncthreads();

    // ---- emit paired layout (same formulas/order as the verified kernel).
    float* outp = ws + (size_t)b * WEFF_STRIDE;
    if (l < 2) {
        const int base = l * 1024;
        for (int idx = tid; idx < 1024; idx += 256) {
            const int o2 = idx >> 6, rem = idx & 63, i = rem >> 1, h = rem & 1;
            const int oo = o2 + 16 * h;
            outp[base + idx] = w[oo * 32 + i] * st[i] * dem[oo];
        }
    } else {
        if (tid < 96) {
            const int oo = tid >> 5, i = tid & 31;
            outp[2048 + tid] = w[tid] * st[i] * dem[oo];
        }
    }
}

// ---------------------------------------------------------------------------
// Kernel B: EXACT round-0 structure (1 px/thread, 2048 blocks, no LDS, no
// barriers — the measured best at 52.5 us) with ONE change: the feat-gather
// phase batches 4 levels at a time (16 loads issued together, then 4 blends)
// instead of load->blend per level. 4x fewer exposed vmcnt waits; blend
// formulas and order bit-identical to round 0. MLP untouched.
// ---------------------------------------------------------------------------
__global__ __launch_bounds__(256) void fused_kernel(
    const float* __restrict__ tables,   // [B, L, T, 2]
    const float* __restrict__ coords,   // [N, 2]
    const float* __restrict__ weff,     // ws: paired weights per batch
    const float* __restrict__ b0, const float* __restrict__ b1, const float* __restrict__ b2,
    float* __restrict__ out,            // [B, 3, 256, 256]
    ResPack res)
{
    const int b     = blockIdx.x & 7;           // XCD-affinity: batch <-> XCD
    const int chunk = blockIdx.x >> 3;
    const int n     = chunk * 256 + (int)threadIdx.x;

    const float cx = coords[2 * n];
    const float cy = coords[2 * n + 1];
    const float* tb = tables + (size_t)b * (LVL * TBL * 2);

    float feat[32];

    // ---- gather phase: groups of 4 levels, 16 loads in flight per group ----
    #pragma unroll
    for (int lg = 0; lg < 4; ++lg) {
        float2 g[16];
        float fxs[4], fys[4];

        #pragma unroll
        for (int j = 0; j < 4; ++j) {
            const int l = lg * 4 + j;
            const int R = res.r[l];
            const float rm1 = (float)(R - 1);
            const float px = cx * rm1, py = cy * rm1;
            const float fpx = floorf(px), fpy = floorf(py);
            fxs[j] = px - fpx; fys[j] = py - fpy;
            unsigned x0 = (unsigned)fpx, y0 = (unsigned)fpy;
            const unsigned im = (unsigned)(R - 1);
            unsigned x1 = x0 + 1u; if (x1 > im) x1 = im;
            unsigned y1 = y0 + 1u; if (y1 > im) y1 = im;
            const unsigned hy0 = y0 * HPRIME, hy1 = y1 * HPRIME;
            const float2* tl = (const float2*)(tb + l * (TBL * 2));
            g[4 * j + 0] = tl[(x0 ^ hy0) & 0xFFFFu];
            g[4 * j + 1] = tl[(x1 ^ hy0) & 0xFFFFu];
            g[4 * j + 2] = tl[(x0 ^ hy1) & 0xFFFFu];
            g[4 * j + 3] = tl[(x1 ^ hy1) & 0xFFFFu];
        }

        #pragma unroll
        for (int j = 0; j < 4; ++j) {
            const int l = lg * 4 + j;
            const float fx = fxs[j], fy = fys[j];
            const float w00 = (1.f - fx) * (1.f - fy);
            const float w10 = fx * (1.f - fy);
            const float w01 = (1.f - fx) * fy;
            const float w11 = fx * fy;
            const float2 g00 = g[4 * j + 0];
            const float2 g10 = g[4 * j + 1];
            const float2 g01 = g[4 * j + 2];
            const float2 g11 = g[4 * j + 3];
            feat[2 * l]     = g00.x * w00 + g10.x * w10 + g01.x * w01 + g11.x * w11;
            feat[2 * l + 1] = g00.y * w00 + g10.y * w10 + g01.y * w01 + g11.y * w11;
        }
    }

    const f32x2* W0p = (const f32x2*)(weff + (size_t)b * WEFF_STRIDE);         // [16][32]
    const f32x2* W1p = W0p + 512;                                              // [16][32]
    const float* W2  = weff + (size_t)b * WEFF_STRIDE + 2048;                  // [3][32]

    // layer 0: paired outputs {o2, o2+16}
    f32x2 h1p[16];
    #pragma unroll
    for (int o2 = 0; o2 < 16; ++o2) {
        f32x2 acc; acc[0] = b0[o2]; acc[1] = b0[o2 + 16];
        #pragma unroll
        for (int i = 0; i < 32; ++i) {
            f32x2 fb; fb[0] = feat[i]; fb[1] = feat[i];
            acc += W0p[o2 * 32 + i] * fb;
        }
        acc[0] = fmaxf(acc[0], 0.f); acc[1] = fmaxf(acc[1], 0.f);
        h1p[o2] = acc;
    }

    // layer 1
    f32x2 h2p[16];
    #pragma unroll
    for (int o2 = 0; o2 < 16; ++o2) {
        f32x2 acc; acc[0] = b1[o2]; acc[1] = b1[o2 + 16];
        #pragma unroll
        for (int i = 0; i < 32; ++i) {
            const float hv = h1p[i & 15][i >> 4];
            f32x2 fb; fb[0] = hv; fb[1] = hv;
            acc += W1p[o2 * 32 + i] * fb;
        }
        acc[0] = fmaxf(acc[0], 0.f); acc[1] = fmaxf(acc[1], 0.f);
        h2p[o2] = acc;
    }

    // layer 2 (3 outputs, scalar)
    #pragma unroll
    for (int o = 0; o < 3; ++o) {
        float acc = b2[o];
        #pragma unroll
        for (int i = 0; i < 32; ++i)
            acc = fmaf(W2[o * 32 + i], h2p[i & 15][i >> 4], acc);
        out[((size_t)(b * 3 + o) << 16) + n] = tanhf(acc);
    }
}

// ---------------------------------------------------------------------------
extern "C" void kernel_launch(void* const* d_in, const int* in_sizes, int n_in,
                              void* d_out, int out_size, void* d_ws, size_t ws_size,
                              hipStream_t stream) {
    const float* x      = (const float*)d_in[0];
    const float* s      = (const float*)d_in[1];
    const float* coords = (const float*)d_in[2];
    const float* w0  = (const float*)d_in[3];
    const float* aw0 = (const float*)d_in[4];
    const float* ab0 = (const float*)d_in[5];
    const float* b0  = (const float*)d_in[6];
    const float* w1  = (const float*)d_in[7];
    const float* aw1 = (const float*)d_in[8];
    const float* ab1 = (const float*)d_in[9];
    const float* b1  = (const float*)d_in[10];
    const float* w2  = (const float*)d_in[11];
    const float* aw2 = (const float*)d_in[12];
    const float* ab2 = (const float*)d_in[13];
    const float* b2  = (const float*)d_in[14];
    float* out = (float*)d_out;
    float* ws  = (float*)d_ws;    // 17152 floats used

    ResPack rp;
    const double g = pow(256.0 / 16.0, 1.0 / 15.0);
    for (int l = 0; l < LVL; ++l) {
        double r = 16.0 * pow(g, (double)l);
        long ri = lround(r);
        if (ri > 256) ri = 256;
        rp.r[l] = (int)ri;
    }

    hipLaunchKernelGGL(weff_kernel, dim3(24), dim3(256), 0, stream,
                       s, aw0, ab0, aw1, ab1, aw2, ab2, w0, w1, w2, ws);
    hipLaunchKernelGGL(fused_kernel, dim3(NPIX / 256 * BATCH), dim3(256), 0, stream,
                       x, coords, ws, b0, b1, b2, out, rp);
}